// Round 6
// baseline (642.033 us; speedup 1.0000x reference)
//
#include <hip/hip_runtime.h>
#include <hip/hip_bf16.h>

typedef unsigned short u16;
typedef short bf16x8 __attribute__((ext_vector_type(8)));
typedef float f32x16 __attribute__((ext_vector_type(16)));
typedef unsigned short u16x8 __attribute__((ext_vector_type(8)));
typedef unsigned short u16x4 __attribute__((ext_vector_type(4)));

__device__ __forceinline__ u16 f2bf(float f) {
    unsigned u = __float_as_uint(f);
    return (u16)((u + 0x7FFFu + ((u >> 16) & 1u)) >> 16);  // RNE, no NaNs here
}
__device__ __forceinline__ float bf2f(u16 h) {
    return __uint_as_float(((unsigned)h) << 16);
}

// ---------------------------------------------------------------------------
// Elementwise fp32 -> bf16 cast (x). n4 = elements/4.
// ---------------------------------------------------------------------------
__global__ __launch_bounds__(256) void cast_f32_bf16(const float4* __restrict__ src,
                                                     ushort4* __restrict__ dst, int n4) {
    int i = blockIdx.x * 256 + threadIdx.x;
    if (i < n4) {
        float4 v = src[i];
        ushort4 o;
        o.x = f2bf(v.x); o.y = f2bf(v.y); o.z = f2bf(v.z); o.w = f2bf(v.w);
        dst[i] = o;
    }
}

// ---------------------------------------------------------------------------
// 3x 1024x1024 fp32 -> bf16 transpose in one dispatch (z selects weight)
// ---------------------------------------------------------------------------
__global__ __launch_bounds__(256) void transpose_cast3(const float* __restrict__ W0,
                                                       const float* __restrict__ W1,
                                                       const float* __restrict__ W2,
                                                       u16* __restrict__ WT) {
    __shared__ float t[32][33];
    const float* W = (blockIdx.z == 0) ? W0 : (blockIdx.z == 1) ? W1 : W2;
    u16* Wt = WT + (long)blockIdx.z * 1048576;
    int bx = blockIdx.x * 32;  // n
    int by = blockIdx.y * 32;  // k
    int tx = threadIdx.x, ty = threadIdx.y;
    for (int r = ty; r < 32; r += 8)
        t[r][tx] = W[(by + r) * 1024 + bx + tx];
    __syncthreads();
    for (int r = ty; r < 32; r += 8)
        Wt[(long)(bx + r) * 1024 + by + tx] = f2bf(t[tx][r]);
}

// ---------------------------------------------------------------------------
// 256x256-tile bf16 MFMA GEMM, B^T input: C = A[M,K] * Bt[N,K]^T
// 512 threads = 8 waves (2M x 4N); per wave 128x64 of C = 4x2 tiles of
// mfma_f32_32x32x16_bf16 (acc 4x2 f32x16 = 128 AGPRs).
//
// BK=64, 2-buffer LDS dbuf (2 x 64 KiB), 4 phases per K-tile, phase p = one
// K-step of 16 (k-plane pair {2p, 2p+1}):
//   VMB(6) [counted vmcnt + barrier]  -> guarantees group p of tile t landed
//   stage group p of tile t+1 (2 GLL: A + B k-plane pair)
//   ds_read 6 frags (4 A-strips + 2 B-strips, 1 b128 each)
//   setprio(1); 8 MFMA; setprio(0)
// Staging groups ARE phase-consumption sets (k-plane pairs) -> per-phase
// vmcnt(6) with in-order retirement gives exact guarantees; steady state
// never drains (3 groups in flight). Last tile peels 6/4/2/0.
//
// LDS layout is K-PLANE-MAJOR: plane c (8 bf16 of K) at base c*2048 u16,
// element (c, row) at c*2048 + row*8. Fragment ds_read_b128: lanes 0..31
// read 32 consecutive rows = base+16*lane bytes -> conflict-free by
// construction, no swizzle. GLL dest: thread tid writes plane 2g+(tid>>8),
// row tid&255 -> dest = g*4096 + tid*8 (linear, wave-uniform+lane*16 ok).
//
// MODE 0: fused QKV. cols<2048 -> bf16+bias into QK[16384][2048];
//         cols>=2048 -> bf16+bias TRANSPOSED into Vt[b][1024][2048].
// MODE 2: bf16 out * scale (scores). MODE 3: fp32 out (attn @ V).
// 32x32 C/D layout: col=lane&31, row=(reg&3)+8*(reg>>2)+4*(lane>>5).
// ---------------------------------------------------------------------------
#define GLL16(g, l)                                                     \
    __builtin_amdgcn_global_load_lds(                                   \
        (const __attribute__((address_space(1))) void*)(g),             \
        (__attribute__((address_space(3))) void*)(l), 16, 0, 0)

#define VMB(n)                                                          \
    do {                                                                \
        asm volatile("s_waitcnt vmcnt(" #n ")" ::: "memory");           \
        __builtin_amdgcn_s_barrier();                                   \
    } while (0)

template <int MODE>
__global__ __launch_bounds__(512, 2)
void gemm_bt(const u16* __restrict__ A, int lda, long sA,
             const u16* __restrict__ Bt, int ldb, long sB,
             const float* __restrict__ bq_, const float* __restrict__ bk_,
             const float* __restrict__ bv_,
             void* __restrict__ Cout, void* __restrict__ Cout2,
             int ldc, long sC, int Kdim, float scale)
{
    // dbuf: per buffer A 8 planes x 256 rows x 8 u16 (16384) ++ B same
    __shared__ __align__(16) u16 lds[2 * 32768];

    const int tid  = threadIdx.x;
    const int wave = tid >> 6;
    const int lane = tid & 63;
    const int m32  = lane & 31;
    const int hi5  = lane >> 5;

    // XCD swizzle: flat%8 -> XCD; contiguous tile span per XCD (totals %8==0)
    const int gx = gridDim.x, gy = gridDim.y;
    int flat = (blockIdx.z * gy + blockIdx.y) * gx + blockIdx.x;
    int total = gx * gy * gridDim.z;
    int tile = (flat & 7) * (total >> 3) + (flat >> 3);
    const int bx = tile % gx;
    const int by = (tile / gx) % gy;
    const int bz = tile / (gx * gy);

    const u16* Ab = A + (long)bz * sA;
    const u16* Bb = Bt + (long)bz * sB;
    const int row0 = by * 256;
    const int col0 = bx * 256;
    const int wr = (wave & 1) * 128;   // 2 waves in M
    const int wc = (wave >> 1) * 64;   // 4 waves in N

    // staging constants: thread covers (plane 2g + (tid>>8), row tid&255)
    const int r255 = tid & 255;
    const int hp   = tid >> 8;
    const u16* paA = Ab + (long)(row0 + r255) * lda + hp * 8;
    const u16* pbB = Bb + (long)(col0 + r255) * ldb + hp * 8;
    const int dst8 = tid * 8;   // u16 offset within a group's plane-pair

    // fragment read bases (u16 offsets into one dbuf buffer)
    const int aoff = hi5 * 2048 + (wr + m32) * 8;            // A plane base
    const int boff = 16384 + hi5 * 2048 + (wc + m32) * 8;    // B plane base

    f32x16 acc[4][2] = {};

#define STAGE_G(t, g)                                                       \
    do {                                                                    \
        u16* lb_ = &lds[((t) & 1) * 32768];                                 \
        const long ko_ = (long)(t) * 64 + (g) * 16;                         \
        GLL16(paA + ko_, lb_ + (g) * 4096 + dst8);                          \
        GLL16(pbB + ko_, lb_ + 16384 + (g) * 4096 + dst8);                  \
    } while (0)

#define READ_MMA(lb_, p)                                                    \
    do {                                                                    \
        bf16x8 af[4], bfr[2];                                               \
        _Pragma("unroll") for (int i = 0; i < 4; ++i)                       \
            af[i] = *(const bf16x8*)&(lb_)[(p) * 4096 + aoff + i * 256];    \
        _Pragma("unroll") for (int j = 0; j < 2; ++j)                       \
            bfr[j] = *(const bf16x8*)&(lb_)[(p) * 4096 + boff + j * 256];   \
        __builtin_amdgcn_s_setprio(1);                                      \
        _Pragma("unroll") for (int i = 0; i < 4; ++i)                       \
        _Pragma("unroll") for (int j = 0; j < 2; ++j)                       \
            acc[i][j] = __builtin_amdgcn_mfma_f32_32x32x16_bf16(            \
                af[i], bfr[j], acc[i][j], 0, 0, 0);                         \
        __builtin_amdgcn_s_setprio(0);                                      \
    } while (0)

    const int NT = Kdim >> 6;   // K-tiles of 64 (NT >= 16 here)
    STAGE_G(0, 0); STAGE_G(0, 1); STAGE_G(0, 2); STAGE_G(0, 3);

    for (int t = 0; t < NT - 1; ++t) {
        const u16* lb = &lds[(t & 1) * 32768];
#pragma unroll
        for (int p = 0; p < 4; ++p) {
            VMB(6);                 // group p of tile t landed block-wide
            STAGE_G(t + 1, p);      // safe: barrier above proves buf (t+1)&1
                                    // readers (tile t-1) are all done
            READ_MMA(lb, p);
        }
    }
    {   // last tile: no staging, tightening counts
        const u16* lb = &lds[((NT - 1) & 1) * 32768];
        VMB(6); READ_MMA(lb, 0);
        VMB(4); READ_MMA(lb, 1);
        VMB(2); READ_MMA(lb, 2);
        VMB(0); READ_MMA(lb, 3);
    }

    // epilogue: 32x32 C/D layout col=lane&31, row=(reg&3)+8*(reg>>2)+4*hi5
    if (MODE == 0) {
        if (col0 < 2048) {
            const float* bp = (col0 < 1024) ? bq_ : bk_;
#pragma unroll
            for (int i = 0; i < 4; ++i) {
#pragma unroll
                for (int j = 0; j < 2; ++j) {
                    int col = col0 + wc + j * 32 + m32;
                    float badd = bp[col & 1023];
#pragma unroll
                    for (int g = 0; g < 4; ++g) {
                        int rbase = row0 + wr + i * 32 + 4 * hi5 + 8 * g;
#pragma unroll
                        for (int rr = 0; rr < 4; ++rr)
                            ((u16*)Cout)[(long)(rbase + rr) * 2048 + col] =
                                f2bf(acc[i][j][g * 4 + rr] + badd);
                    }
                }
            }
        } else {
            // V part: store transposed into Vt[b][1024][2048], 4 rows packed
#pragma unroll
            for (int i = 0; i < 4; ++i) {
#pragma unroll
                for (int j = 0; j < 2; ++j) {
                    int d = col0 + wc + j * 32 + m32 - 2048;
                    float badd = bv_[d];
#pragma unroll
                    for (int g = 0; g < 4; ++g) {
                        int rbase = row0 + wr + i * 32 + 4 * hi5 + 8 * g;
                        int b = rbase >> 11, m = rbase & 2047;
                        u16x4 pk;
#pragma unroll
                        for (int rr = 0; rr < 4; ++rr)
                            pk[rr] = f2bf(acc[i][j][g * 4 + rr] + badd);
                        *(u16x4*)((u16*)Cout2 + ((long)b << 21) + ((long)d << 11) + m) = pk;
                    }
                }
            }
        }
    } else {
#pragma unroll
        for (int i = 0; i < 4; ++i) {
#pragma unroll
            for (int j = 0; j < 2; ++j) {
                int col = col0 + wc + j * 32 + m32;
#pragma unroll
                for (int g = 0; g < 4; ++g) {
                    int rbase = row0 + wr + i * 32 + 4 * hi5 + 8 * g;
#pragma unroll
                    for (int rr = 0; rr < 4; ++rr) {
                        long idx = (long)bz * sC + (long)(rbase + rr) * ldc + col;
                        float v = acc[i][j][g * 4 + rr];
                        if (MODE == 2)
                            ((u16*)Cout)[idx] = f2bf(v * scale);
                        else
                            ((float*)Cout)[idx] = v;
                    }
                }
            }
        }
    }
}

// ---------------------------------------------------------------------------
// In-place row softmax over bf16 [16384 rows][2048], one block per row.
// ---------------------------------------------------------------------------
__global__ __launch_bounds__(256) void softmax_rows(u16* __restrict__ S) {
    __shared__ float red[4];
    const long row = blockIdx.x;
    u16* p = S + row * 2048;
    const int tid = threadIdx.x;
    const int lane = tid & 63, wv = tid >> 6;

    u16x8 raw = *(const u16x8*)(p + tid * 8);
    float v[8];
#pragma unroll
    for (int i = 0; i < 8; ++i) v[i] = bf2f(raw[i]);

    float m = -1e30f;
#pragma unroll
    for (int i = 0; i < 8; ++i) m = fmaxf(m, v[i]);
    for (int off = 32; off > 0; off >>= 1) m = fmaxf(m, __shfl_down(m, off));
    if (lane == 0) red[wv] = m;
    __syncthreads();
    m = fmaxf(fmaxf(red[0], red[1]), fmaxf(red[2], red[3]));

    float s = 0.0f;
#pragma unroll
    for (int i = 0; i < 8; ++i) { v[i] = __expf(v[i] - m); s += v[i]; }
    for (int off = 32; off > 0; off >>= 1) s += __shfl_down(s, off);
    __syncthreads();
    if (lane == 0) red[wv] = s;
    __syncthreads();
    s = red[0] + red[1] + red[2] + red[3];
    float inv = 1.0f / s;

    u16x8 o;
#pragma unroll
    for (int i = 0; i < 8; ++i) o[i] = f2bf(v[i] * inv);
    *(u16x8*)(p + tid * 8) = o;
}

// ---------------------------------------------------------------------------
extern "C" void kernel_launch(void* const* d_in, const int* in_sizes, int n_in,
                              void* d_out, int out_size, void* d_ws, size_t ws_size,
                              hipStream_t stream) {
    const float* x  = (const float*)d_in[0];
    const float* Wq = (const float*)d_in[1];
    const float* bq = (const float*)d_in[2];
    const float* Wk = (const float*)d_in[3];
    const float* bk = (const float*)d_in[4];
    const float* Wv = (const float*)d_in[5];
    const float* bv = (const float*)d_in[6];
    float* out = (float*)d_out;

    // workspace layout (bytes)
    char* ws = (char*)d_ws;
    u16* xb = (u16*)(ws);                        // 16384x1024 bf16   = 32 MiB
    u16* WT = (u16*)(ws + 33554432);             // 3072x1024 bf16    =  6 MiB
    u16* QK = (u16*)(ws + 39845888);             // 16384x2048 bf16   = 64 MiB
    u16* Vt = (u16*)(ws + 106954752);            // 8 x 1024x2048 bf16= 32 MiB
    u16* S  = (u16*)(ws + 140509184);            // 8 x 2048x2048 bf16= 64 MiB
    // total 207,618,048 bytes

    // 1) casts
    cast_f32_bf16<<<16384, 256, 0, stream>>>((const float4*)x, (ushort4*)xb, 4194304);
    dim3 tg(32, 32, 3), tb(32, 8);
    transpose_cast3<<<tg, tb, 0, stream>>>(Wq, Wk, Wv, WT);

    // 2) fused QKV projection: [16384,3072] = xb @ WT^T + b   (768 blocks)
    dim3 gp(12, 64, 1);
    gemm_bt<0><<<gp, 512, 0, stream>>>(xb, 1024, 0, WT, 1024, 0,
                                       bq, bk, bv, QK, Vt, 0, 0, 1024, 1.0f);

    // 3) scores S[b] = (Q[b] @ K[b]^T) / 32, bf16   (512 blocks)
    dim3 gs(8, 8, 8);
    gemm_bt<2><<<gs, 512, 0, stream>>>(QK, 2048, 2048L * 2048, QK + 1024, 2048, 2048L * 2048,
                                       nullptr, nullptr, nullptr, S, nullptr,
                                       2048, 2048L * 2048, 1024, 0.03125f);

    // 4) row softmax in place
    softmax_rows<<<16384, 256, 0, stream>>>(S);

    // 5) out[b] = P[b] @ V[b]   (via Vt, fp32 out; 256 blocks)
    dim3 gv(4, 8, 8);
    gemm_bt<3><<<gv, 512, 0, stream>>>(S, 2048, 2048L * 2048, Vt, 2048, 1024L * 2048,
                                       nullptr, nullptr, nullptr, out, nullptr,
                                       1024, 2048L * 1024, 2048, 1.0f);
}